// Round 4
// baseline (1091.588 us; speedup 1.0000x reference)
//
#include <hip/hip_runtime.h>

// B=16,S=1024,E=1024,F=4096,H=16,D=64. N = B*S = 16384 tokens.
// Pipeline: LN1 -> QKV gemm(bf16 MFMA)+bias -> MFMA flash attn -> proj gemm+bias+resid -> d_out
//           -> LN2 -> [2 row-chunks] lin1 gemm+bias+GELU -> lin2 gemm+bias+resid(in-place d_out)
//
// Workspace plan (peak ~152 MB):
//   0          wqkv_b  bf16 3072x1024   (6 MB)
//   6291456    wo_b    bf16 1024x1024   (2 MB)
//   8388608    w1_b    bf16 4096x1024   (8 MB)
//   16777216   w2_b    bf16 1024x4096   (8 MB)
//   25165824   region1 (32 MB): xn_b -> ctx_b -> xn2_b
//   58720256   region2 (96 MB): qkv_b -> h chunk (64 MB, FFN in 2 row-chunks)
// x1 (fp32) lives in d_out; lin2 updates d_out in place (same-thread R->W).

typedef __attribute__((ext_vector_type(8))) short bf16x8;
typedef __attribute__((ext_vector_type(4))) float f32x4;
typedef __attribute__((ext_vector_type(8))) unsigned short u16x8;
typedef __attribute__((ext_vector_type(4))) unsigned short u16x4;

__device__ __forceinline__ float bf2f(unsigned short u) {
    return __uint_as_float(((unsigned int)u) << 16);
}
__device__ __forceinline__ unsigned short f2bf(float f) {
    unsigned int u = __float_as_uint(f);
    u += 0x7fffu + ((u >> 16) & 1u);   // RNE
    return (unsigned short)(u >> 16);
}

// async global->LDS, 16 B per lane; LDS dest is wave-uniform base + lane*16
__device__ __forceinline__ void gload_lds16(const unsigned short* g, unsigned short* l) {
    __builtin_amdgcn_global_load_lds(
        (const __attribute__((address_space(1))) unsigned int*)g,
        (__attribute__((address_space(3))) unsigned int*)l, 16, 0, 0);
}

// ---------------- fp32 -> bf16 weight conversion ----------------
__global__ __launch_bounds__(256) void cvt_kernel(const float* __restrict__ in,
                                                  unsigned short* __restrict__ out, int n4) {
    int i = blockIdx.x * 256 + threadIdx.x;
    if (i >= n4) return;
    float4 v = ((const float4*)in)[i];
    u16x4 o;
    o[0] = f2bf(v.x); o[1] = f2bf(v.y); o[2] = f2bf(v.z); o[3] = f2bf(v.w);
    ((u16x4*)out)[i] = o;
}

// ---------------- LayerNorm (E=1024), fp32 in -> bf16 out ----------------
__global__ __launch_bounds__(256) void ln_kernel(const float* __restrict__ x,
                                                 const float* __restrict__ w,
                                                 const float* __restrict__ b,
                                                 unsigned short* __restrict__ out) {
    const int row = blockIdx.x;
    const int t = threadIdx.x;
    const float* xr = x + (size_t)row * 1024;
    float4 v = *(const float4*)(xr + t * 4);
    float s = v.x + v.y + v.z + v.w;
    float sq = v.x * v.x + v.y * v.y + v.z * v.z + v.w * v.w;
#pragma unroll
    for (int off = 32; off > 0; off >>= 1) {
        s += __shfl_xor(s, off);
        sq += __shfl_xor(sq, off);
    }
    __shared__ float rs_[4], rq_[4];
    if ((t & 63) == 0) { rs_[t >> 6] = s; rq_[t >> 6] = sq; }
    __syncthreads();
    s = rs_[0] + rs_[1] + rs_[2] + rs_[3];
    sq = rq_[0] + rq_[1] + rq_[2] + rq_[3];
    const float mu = s * (1.0f / 1024.0f);
    const float var = sq * (1.0f / 1024.0f) - mu * mu;
    const float rstd = rsqrtf(var + 1e-5f);
    const int c = t * 4;
    float4 wv = *(const float4*)(w + c);
    float4 bv = *(const float4*)(b + c);
    u16x4 o;
    o[0] = f2bf((v.x - mu) * rstd * wv.x + bv.x);
    o[1] = f2bf((v.y - mu) * rstd * wv.y + bv.y);
    o[2] = f2bf((v.z - mu) * rstd * wv.z + bv.z);
    o[3] = f2bf((v.w - mu) * rstd * wv.w + bv.w);
    *(u16x4*)(out + (size_t)row * 1024 + c) = o;
}

// ---------------- bf16 MFMA GEMM: C[M,N] = A[M,K] @ Bt[N,K]^T + epilogue ----------------
// 128x128 tile, BK=32, 256 threads (4 waves, 2x2 of 64x64), 4x4 16x16x32 MFMAs per wave.
// Staging via global_load_lds width=16 (m97 structure): inst u of wave w fills LDS slots
// (w*2+u)*64+lane, i.e. row = w*32+u*16+(lane>>2), 16B chunk c = lane&3 of [128][32] tiles.
// EPI: 0 = bias -> bf16 ; 1 = bias + resid -> f32 ; 2 = bias + exact GELU -> bf16
template <int EPI>
__global__ __launch_bounds__(256) void gemm_bt(const unsigned short* __restrict__ A,
                                               const unsigned short* __restrict__ Bt,
                                               const float* __restrict__ bias,
                                               const float* __restrict__ resid,
                                               void* __restrict__ outp,
                                               int M, int N, int K) {
    __shared__ __align__(16) unsigned short sA[128 * 32];
    __shared__ __align__(16) unsigned short sB[128 * 32];
    const int t = threadIdx.x;
    const int lane = t & 63;
    const int w = t >> 6;
    const int wm = (w >> 1) * 64;
    const int wn = (w & 1) * 64;
    const int quad = lane >> 4;
    const int cl = lane & 15;
    const int mBase = blockIdx.y * 128;
    const int nBase = blockIdx.x * 128;

    // per-lane global source for async staging
    const int rl = lane >> 2;   // row within 16-row group
    const int cc = lane & 3;    // 16B chunk
    const unsigned short* gA = A + (size_t)(mBase + w * 32 + rl) * K + cc * 8;
    const unsigned short* gB = Bt + (size_t)(nBase + w * 32 + rl) * K + cc * 8;

    f32x4 acc[4][4] = {};

    for (int k0 = 0; k0 < K; k0 += 32) {
#pragma unroll
        for (int u = 0; u < 2; ++u) {
            gload_lds16(gA + (size_t)u * 16 * K + k0, sA + (w * 2 + u) * 512);
            gload_lds16(gB + (size_t)u * 16 * K + k0, sB + (w * 2 + u) * 512);
        }
        __syncthreads();
        bf16x8 af[4], bfr[4];
#pragma unroll
        for (int i = 0; i < 4; ++i) {
            af[i] = *(const bf16x8*)(sA + (wm + i * 16 + cl) * 32 + quad * 8);
            bfr[i] = *(const bf16x8*)(sB + (wn + i * 16 + cl) * 32 + quad * 8);
        }
#pragma unroll
        for (int i = 0; i < 4; ++i)
#pragma unroll
            for (int j = 0; j < 4; ++j)
                acc[i][j] =
                    __builtin_amdgcn_mfma_f32_16x16x32_bf16(af[i], bfr[j], acc[i][j], 0, 0, 0);
        __syncthreads();
    }

    // C/D layout: col = lane&15, row = quad*4 + reg
#pragma unroll
    for (int i = 0; i < 4; ++i) {
        const int rowg = mBase + wm + i * 16 + quad * 4;
#pragma unroll
        for (int j = 0; j < 4; ++j) {
            const int colg = nBase + wn + j * 16 + cl;
            const float bv = bias[colg];
#pragma unroll
            for (int rr = 0; rr < 4; ++rr) {
                const float v = acc[i][j][rr] + bv;
                const size_t idx = (size_t)(rowg + rr) * N + colg;
                if constexpr (EPI == 0) {
                    ((unsigned short*)outp)[idx] = f2bf(v);
                } else if constexpr (EPI == 1) {
                    ((float*)outp)[idx] = v + resid[idx];
                } else {
                    const float g = 0.5f * v * (1.0f + erff(v * 0.70710678118654752f));
                    ((unsigned short*)outp)[idx] = f2bf(g);
                }
            }
        }
    }
}

// ---------------- MFMA flash attention ----------------
// Block = 256 threads (4 waves). blockIdx.x = b*16+h, blockIdx.y = q-tile (64 rows).
// Wave w owns q-rows qt*64 + w*16 .. +15. Per 64-key tile:
//   QK^T: A=Q frags (regs), B=K from LDS [key][72] -> S 16x64 in C-layout (4 f32x4)
//   online softmax in-register (scale 1/8 folded into exp fma; row state per quad)
//   P -> wave-private LDS rows [16][72] (C-layout write, A-layout b128 read)
//   PV: B=V^T stored as key-pair dwords [d][36], group-swizzled by (kp>>2)^(d>>3)
// LDS: Ks 9216 + Vt 9216 + Ps 9216 = 27.6 KB. 2 barriers/tile.
__global__ __launch_bounds__(256) void attn_mfma(const unsigned short* __restrict__ qkv,
                                                 unsigned short* __restrict__ ctx) {
    __shared__ __align__(16) unsigned short Ks[64 * 72];
    __shared__ __align__(16) unsigned int Vt[64 * 36];
    __shared__ __align__(16) unsigned short Ps[64 * 72];

    const int bh = blockIdx.x;
    const int qt = blockIdx.y;
    const int b = bh >> 4;
    const int h = bh & 15;
    const int t = threadIdx.x;
    const int w = t >> 6;
    const int lane = t & 63;
    const int quad = lane >> 4;
    const int cl = lane & 15;
    const size_t tok0 = (size_t)b * 1024;

    // Q fragments (A-layout): m = cl (wave q-row), k = quad*8 + ks*32
    bf16x8 aq[2];
    {
        const unsigned short* qp =
            qkv + (tok0 + qt * 64 + w * 16 + cl) * 3072 + h * 64 + quad * 8;
        aq[0] = *(const bf16x8*)(qp);
        aq[1] = *(const bf16x8*)(qp + 32);
    }

    // staging indices
    const int r0 = t >> 2;         // K row 0..63
    const int c16 = (t & 3) * 16;  // K col chunk
    const int kp = t >> 3;         // V key-pair 0..31
    const int dc = t & 7;          // V d-chunk (8 d's)

    f32x4 acc[4] = {};             // PV accum: C rows quad*4+rr (q), cols j*16+cl (d)
    float m_r[4], l_r[4];
#pragma unroll
    for (int rr = 0; rr < 4; ++rr) { m_r[rr] = -3.0e38f; l_r[rr] = 0.0f; }

    for (int kt = 0; kt < 16; ++kt) {
        // ---- stage K [key][d] and V^T [d][key-pair dword] ----
        {
            const unsigned short* kg =
                qkv + (tok0 + kt * 64 + r0) * 3072 + 1024 + h * 64 + c16;
            *(int4*)(Ks + r0 * 72 + c16) = *(const int4*)(kg);
            *(int4*)(Ks + r0 * 72 + c16 + 8) = *(const int4*)(kg + 8);

            const unsigned short* vg =
                qkv + (tok0 + kt * 64 + 2 * kp) * 3072 + 2048 + h * 64 + dc * 8;
            u16x8 v0 = *(const u16x8*)(vg);
            u16x8 v1 = *(const u16x8*)(vg + 3072);
            const int g = kp >> 2, wd = kp & 3;
#pragma unroll
            for (int j = 0; j < 8; ++j) {
                const int d = dc * 8 + j;
                Vt[d * 36 + (((g ^ (d >> 3)) << 2) | wd)] =
                    ((unsigned int)v1[j] << 16) | (unsigned int)v0[j];
            }
        }
        __syncthreads();

        // ---- QK^T ----
        f32x4 sc[4] = {};
#pragma unroll
        for (int i = 0; i < 4; ++i) {
            const int rb = i * 16 + cl;
#pragma unroll
            for (int ks = 0; ks < 2; ++ks) {
                bf16x8 bk = *(const bf16x8*)(Ks + rb * 72 + quad * 8 + ks * 32);
                sc[i] = __builtin_amdgcn_mfma_f32_16x16x32_bf16(aq[ks], bk, sc[i], 0, 0, 0);
            }
        }

        // ---- online softmax (rows quad*4+rr; reduce across 16 lanes of quad) ----
        float p[4][4];
#pragma unroll
        for (int rr = 0; rr < 4; ++rr) {
            float rmax = fmaxf(fmaxf(sc[0][rr], sc[1][rr]), fmaxf(sc[2][rr], sc[3][rr]));
#pragma unroll
            for (int off = 1; off < 16; off <<= 1) rmax = fmaxf(rmax, __shfl_xor(rmax, off, 16));
            const float mnew = fmaxf(m_r[rr], rmax * 0.125f);
            const float alpha = __expf(m_r[rr] - mnew);
            m_r[rr] = mnew;
            float psum = 0.0f;
#pragma unroll
            for (int j = 0; j < 4; ++j) {
                p[j][rr] = __expf(fmaf(sc[j][rr], 0.125f, -mnew));
                psum += p[j][rr];
            }
#pragma unroll
            for (int off = 1; off < 16; off <<= 1) psum += __shfl_xor(psum, off, 16);
            l_r[rr] = l_r[rr] * alpha + psum;
#pragma unroll
            for (int j = 0; j < 4; ++j) acc[j][rr] *= alpha;
        }

        // ---- P -> wave-private LDS (C-layout write), re-read in A-layout ----
#pragma unroll
        for (int rr = 0; rr < 4; ++rr)
#pragma unroll
            for (int j = 0; j < 4; ++j)
                Ps[(w * 16 + quad * 4 + rr) * 72 + j * 16 + cl] = f2bf(p[j][rr]);

        // ---- PV ----
#pragma unroll
        for (int ks = 0; ks < 2; ++ks) {
            bf16x8 ap = *(const bf16x8*)(Ps + (w * 16 + cl) * 72 + quad * 8 + ks * 32);
#pragma unroll
            for (int j = 0; j < 4; ++j) {
                const int d = j * 16 + cl;
                bf16x8 bv = *(const bf16x8*)(Vt + d * 36 + (((quad + 4 * ks) ^ (d >> 3)) << 2));
                acc[j] = __builtin_amdgcn_mfma_f32_16x16x32_bf16(ap, bv, acc[j], 0, 0, 0);
            }
        }
        __syncthreads();  // Ks/Vt reads done before next staging
    }

    // ---- epilogue: O = acc / l, bf16 store ----
    float inv[4];
#pragma unroll
    for (int rr = 0; rr < 4; ++rr) inv[rr] = 1.0f / l_r[rr];
#pragma unroll
    for (int rr = 0; rr < 4; ++rr) {
        const size_t tok = tok0 + qt * 64 + w * 16 + quad * 4 + rr;
#pragma unroll
        for (int j = 0; j < 4; ++j)
            ctx[tok * 1024 + h * 64 + j * 16 + cl] = f2bf(acc[j][rr] * inv[rr]);
    }
}

extern "C" void kernel_launch(void* const* d_in, const int* in_sizes, int n_in,
                              void* d_out, int out_size, void* d_ws, size_t ws_size,
                              hipStream_t stream) {
    const float* x    = (const float*)d_in[0];
    const float* wqkv = (const float*)d_in[1];
    const float* bqkv = (const float*)d_in[2];
    const float* wo   = (const float*)d_in[3];
    const float* bo   = (const float*)d_in[4];
    const float* w1   = (const float*)d_in[5];
    const float* b1   = (const float*)d_in[6];
    const float* w2   = (const float*)d_in[7];
    const float* b2   = (const float*)d_in[8];
    const float* n1w  = (const float*)d_in[9];
    const float* n1b  = (const float*)d_in[10];
    const float* n2w  = (const float*)d_in[11];
    const float* n2b  = (const float*)d_in[12];
    float* out = (float*)d_out;   // also serves as x1 (residual stream after attention)

    char* ws = (char*)d_ws;
    unsigned short* wqkv_b = (unsigned short*)(ws);
    unsigned short* wo_b   = (unsigned short*)(ws + 6291456);
    unsigned short* w1_b   = (unsigned short*)(ws + 8388608);
    unsigned short* w2_b   = (unsigned short*)(ws + 16777216);
    unsigned short* r1     = (unsigned short*)(ws + 25165824);  // xn -> ctx -> xn2
    unsigned short* r2     = (unsigned short*)(ws + 58720256);  // qkv -> h chunks

    unsigned short* xn_b  = r1;
    unsigned short* ctx_b = r1;
    unsigned short* xn2_b = r1;
    unsigned short* qkv_b = r2;
    unsigned short* h_b   = r2;

    cvt_kernel<<<3072, 256, 0, stream>>>(wqkv, wqkv_b, 786432);
    cvt_kernel<<<1024, 256, 0, stream>>>(wo, wo_b, 262144);
    cvt_kernel<<<4096, 256, 0, stream>>>(w1, w1_b, 1048576);
    cvt_kernel<<<4096, 256, 0, stream>>>(w2, w2_b, 1048576);

    ln_kernel<<<16384, 256, 0, stream>>>(x, n1w, n1b, xn_b);
    gemm_bt<0><<<dim3(24, 128), 256, 0, stream>>>(xn_b, wqkv_b, bqkv, nullptr, qkv_b,
                                                  16384, 3072, 1024);
    attn_mfma<<<dim3(256, 16), 256, 0, stream>>>(qkv_b, ctx_b);
    gemm_bt<1><<<dim3(8, 128), 256, 0, stream>>>(ctx_b, wo_b, bo, x, out, 16384, 1024, 1024);
    ln_kernel<<<16384, 256, 0, stream>>>(out, n2w, n2b, xn2_b);

    for (int c = 0; c < 2; ++c) {
        const size_t row0 = (size_t)c * 8192;
        gemm_bt<2><<<dim3(32, 64), 256, 0, stream>>>(xn2_b + row0 * 1024, w1_b, b1, nullptr,
                                                     h_b, 8192, 4096, 1024);
        gemm_bt<1><<<dim3(8, 64), 256, 0, stream>>>(h_b, w2_b, b2, out + row0 * 1024,
                                                    out + row0 * 1024, 8192, 1024, 4096);
    }
}

// Round 5
// 1001.784 us; speedup vs baseline: 1.0896x; 1.0896x over previous
//
#include <hip/hip_runtime.h>

// B=16,S=1024,E=1024,F=4096,H=16,D=64. N = B*S = 16384 tokens.
// Pipeline: LN1 -> QKV gemm(bf16 MFMA)+bias -> MFMA flash attn -> proj gemm+bias+resid -> d_out
//           -> LN2 -> [2 row-chunks] lin1 gemm+bias+GELU -> lin2 gemm+bias+resid(in-place d_out)
//
// Workspace plan (peak ~152 MB):
//   0          wqkv_b  bf16 3072x1024   (6 MB)
//   6291456    wo_b    bf16 1024x1024   (2 MB)
//   8388608    w1_b    bf16 4096x1024   (8 MB)
//   16777216   w2_b    bf16 1024x4096   (8 MB)
//   25165824   region1 (32 MB): xn_b -> ctx_b -> xn2_b
//   58720256   region2 (96 MB): qkv_b -> h chunk (64 MB, FFN in 2 row-chunks)
// x1 (fp32) lives in d_out; lin2 updates d_out in place (same-thread R->W).

typedef __attribute__((ext_vector_type(8))) short bf16x8;
typedef __attribute__((ext_vector_type(4))) float f32x4;
typedef __attribute__((ext_vector_type(8))) unsigned short u16x8;
typedef __attribute__((ext_vector_type(4))) unsigned short u16x4;

__device__ __forceinline__ float bf2f(unsigned short u) {
    return __uint_as_float(((unsigned int)u) << 16);
}
__device__ __forceinline__ unsigned short f2bf(float f) {
    unsigned int u = __float_as_uint(f);
    u += 0x7fffu + ((u >> 16) & 1u);   // RNE
    return (unsigned short)(u >> 16);
}

// async global->LDS, 16 B per lane; LDS dest is wave-uniform base + lane*16
__device__ __forceinline__ void gload_lds16(const unsigned short* g, unsigned short* l) {
    __builtin_amdgcn_global_load_lds(
        (const __attribute__((address_space(1))) unsigned int*)g,
        (__attribute__((address_space(3))) unsigned int*)l, 16, 0, 0);
}

// ---------------- fp32 -> bf16 weight conversion ----------------
__global__ __launch_bounds__(256) void cvt_kernel(const float* __restrict__ in,
                                                  unsigned short* __restrict__ out, int n4) {
    int i = blockIdx.x * 256 + threadIdx.x;
    if (i >= n4) return;
    float4 v = ((const float4*)in)[i];
    u16x4 o;
    o[0] = f2bf(v.x); o[1] = f2bf(v.y); o[2] = f2bf(v.z); o[3] = f2bf(v.w);
    ((u16x4*)out)[i] = o;
}

// ---------------- LayerNorm (E=1024), fp32 in -> bf16 out ----------------
__global__ __launch_bounds__(256) void ln_kernel(const float* __restrict__ x,
                                                 const float* __restrict__ w,
                                                 const float* __restrict__ b,
                                                 unsigned short* __restrict__ out) {
    const int row = blockIdx.x;
    const int t = threadIdx.x;
    const float* xr = x + (size_t)row * 1024;
    float4 v = *(const float4*)(xr + t * 4);
    float s = v.x + v.y + v.z + v.w;
    float sq = v.x * v.x + v.y * v.y + v.z * v.z + v.w * v.w;
#pragma unroll
    for (int off = 32; off > 0; off >>= 1) {
        s += __shfl_xor(s, off);
        sq += __shfl_xor(sq, off);
    }
    __shared__ float rs_[4], rq_[4];
    if ((t & 63) == 0) { rs_[t >> 6] = s; rq_[t >> 6] = sq; }
    __syncthreads();
    s = rs_[0] + rs_[1] + rs_[2] + rs_[3];
    sq = rq_[0] + rq_[1] + rq_[2] + rq_[3];
    const float mu = s * (1.0f / 1024.0f);
    const float var = sq * (1.0f / 1024.0f) - mu * mu;
    const float rstd = rsqrtf(var + 1e-5f);
    const int c = t * 4;
    float4 wv = *(const float4*)(w + c);
    float4 bv = *(const float4*)(b + c);
    u16x4 o;
    o[0] = f2bf((v.x - mu) * rstd * wv.x + bv.x);
    o[1] = f2bf((v.y - mu) * rstd * wv.y + bv.y);
    o[2] = f2bf((v.z - mu) * rstd * wv.z + bv.z);
    o[3] = f2bf((v.w - mu) * rstd * wv.w + bv.w);
    *(u16x4*)(out + (size_t)row * 1024 + c) = o;
}

// ---------------- bf16 MFMA GEMM: C[M,N] = A[M,K] @ Bt[N,K]^T + epilogue ----------------
// 128x128 tile, BK=64 (32 KB LDS), 256 threads (4 waves, 2x2 of 64x64), 32 MFMAs per
// barrier pair. Async staging: lane fetches global chunk (lane&7)^(lane>>3) so LDS slot s
// of row r holds chunk s^(r&7) (global-side swizzle; LDS dest must be base+lane*16).
// Fragment read: chunk q of row ra lives at slot q^(ra&7).
// EPI: 0 = bias -> bf16 ; 1 = bias + resid -> f32 ; 2 = bias + exact GELU -> bf16
template <int EPI>
__global__ __launch_bounds__(256) void gemm_bt(const unsigned short* __restrict__ A,
                                               const unsigned short* __restrict__ Bt,
                                               const float* __restrict__ bias,
                                               const float* __restrict__ resid,
                                               void* __restrict__ outp,
                                               int M, int N, int K) {
    __shared__ __align__(16) unsigned short sA[128 * 64];
    __shared__ __align__(16) unsigned short sB[128 * 64];
    const int t = threadIdx.x;
    const int lane = t & 63;
    const int w = t >> 6;
    const int wm = (w >> 1) * 64;
    const int wn = (w & 1) * 64;
    const int quad = lane >> 4;
    const int cl = lane & 15;
    const int mBase = blockIdx.y * 128;
    const int nBase = blockIdx.x * 128;

    // per-lane global source for async staging (8 rows x 8 chunks per inst)
    const int rg = lane >> 3;                 // row within 8-row group
    const int gc = (lane & 7) ^ rg;           // fetched global 16B chunk (swizzled)
    const unsigned short* gA = A + (size_t)(mBase + w * 32 + rg) * K + gc * 8;
    const unsigned short* gB = Bt + (size_t)(nBase + w * 32 + rg) * K + gc * 8;

    f32x4 acc[4][4] = {};

    for (int k0 = 0; k0 < K; k0 += 64) {
#pragma unroll
        for (int u = 0; u < 4; ++u) {
            gload_lds16(gA + (size_t)u * 8 * K + k0, sA + (w * 4 + u) * 512);
            gload_lds16(gB + (size_t)u * 8 * K + k0, sB + (w * 4 + u) * 512);
        }
        __syncthreads();
#pragma unroll
        for (int ks = 0; ks < 2; ++ks) {
            bf16x8 af[4], bfr[4];
#pragma unroll
            for (int i = 0; i < 4; ++i) {
                const int ra = wm + i * 16 + cl;
                af[i] = *(const bf16x8*)(sA + ra * 64 + (((quad + 4 * ks) ^ (ra & 7)) * 8));
                const int rb = wn + i * 16 + cl;
                bfr[i] = *(const bf16x8*)(sB + rb * 64 + (((quad + 4 * ks) ^ (rb & 7)) * 8));
            }
#pragma unroll
            for (int i = 0; i < 4; ++i)
#pragma unroll
                for (int j = 0; j < 4; ++j)
                    acc[i][j] = __builtin_amdgcn_mfma_f32_16x16x32_bf16(af[i], bfr[j],
                                                                        acc[i][j], 0, 0, 0);
        }
        __syncthreads();
    }

    // C/D layout: col = lane&15, row = quad*4 + reg
#pragma unroll
    for (int i = 0; i < 4; ++i) {
        const int rowg = mBase + wm + i * 16 + quad * 4;
#pragma unroll
        for (int j = 0; j < 4; ++j) {
            const int colg = nBase + wn + j * 16 + cl;
            const float bv = bias[colg];
#pragma unroll
            for (int rr = 0; rr < 4; ++rr) {
                const float v = acc[i][j][rr] + bv;
                const size_t idx = (size_t)(rowg + rr) * N + colg;
                if constexpr (EPI == 0) {
                    ((unsigned short*)outp)[idx] = f2bf(v);
                } else if constexpr (EPI == 1) {
                    ((float*)outp)[idx] = v + resid[idx];
                } else {
                    const float g = 0.5f * v * (1.0f + erff(v * 0.70710678118654752f));
                    ((unsigned short*)outp)[idx] = f2bf(g);
                }
            }
        }
    }
}

// ---------------- MFMA flash attention, 128 q-rows per block ----------------
// Block = 256 threads (4 waves). blockIdx.x = b*16+h, blockIdx.y = q-tile (128 rows).
// Wave w owns q-rows qt*128 + w*32 .. +31 (two 16-row sub-tiles). Per 64-key tile:
//   QK^T per sub (8 MFMA), online softmax in-register (scale 1/8 folded into exp);
//   softmax denominator l rides a 5th PV accumulator vs an all-ones B-frag (row-sums
//   via MFMA; alpha-rescale applies automatically; no psum shuffle reduction).
//   P -> wave-private LDS [32 rows][72] -> A-layout b128 read; PV vs V^T key-pair dwords.
// LDS: Ks 9216 + Vt 9216 + Ps 18432 = 36.9 KB. 2 barriers/tile, K/V staged once per 128 q.
__global__ __launch_bounds__(256) void attn_mfma(const unsigned short* __restrict__ qkv,
                                                 unsigned short* __restrict__ ctx) {
    __shared__ __align__(16) unsigned short Ks[64 * 72];
    __shared__ __align__(16) unsigned int Vt[64 * 36];
    __shared__ __align__(16) unsigned short Ps[128 * 72];

    const int bh = blockIdx.x;
    const int qt = blockIdx.y;
    const int b = bh >> 4;
    const int h = bh & 15;
    const int t = threadIdx.x;
    const int w = t >> 6;
    const int lane = t & 63;
    const int quad = lane >> 4;
    const int cl = lane & 15;
    const size_t tok0 = (size_t)b * 1024;
    const int qrow0 = qt * 128 + w * 32;

    // Q fragments (A-layout): m = cl, k = quad*8 + ks*32, two 16-row sub-tiles
    bf16x8 aq[2][2];
#pragma unroll
    for (int sub = 0; sub < 2; ++sub) {
        const unsigned short* qp =
            qkv + (tok0 + qrow0 + sub * 16 + cl) * 3072 + h * 64 + quad * 8;
        aq[sub][0] = *(const bf16x8*)(qp);
        aq[sub][1] = *(const bf16x8*)(qp + 32);
    }

    const bf16x8 vones = {0x3F80, 0x3F80, 0x3F80, 0x3F80, 0x3F80, 0x3F80, 0x3F80, 0x3F80};

    // staging indices
    const int r0 = t >> 2;         // K row 0..63
    const int c16 = (t & 3) * 16;  // K col chunk
    const int kp = t >> 3;         // V key-pair 0..31
    const int dc = t & 7;          // V d-chunk (8 d's)

    f32x4 acc[2][5] = {};          // [sub][j]; j=4 is the l-column (ones B-frag)
    float m_r[2][4];
#pragma unroll
    for (int sub = 0; sub < 2; ++sub)
#pragma unroll
        for (int rr = 0; rr < 4; ++rr) m_r[sub][rr] = -3.0e38f;

    for (int kt = 0; kt < 16; ++kt) {
        // ---- stage K [key][d] and V^T [d][key-pair dword] ----
        {
            const unsigned short* kg =
                qkv + (tok0 + kt * 64 + r0) * 3072 + 1024 + h * 64 + c16;
            *(int4*)(Ks + r0 * 72 + c16) = *(const int4*)(kg);
            *(int4*)(Ks + r0 * 72 + c16 + 8) = *(const int4*)(kg + 8);

            const unsigned short* vg =
                qkv + (tok0 + kt * 64 + 2 * kp) * 3072 + 2048 + h * 64 + dc * 8;
            u16x8 v0 = *(const u16x8*)(vg);
            u16x8 v1 = *(const u16x8*)(vg + 3072);
            const int g = kp >> 2, wd = kp & 3;
#pragma unroll
            for (int j = 0; j < 8; ++j) {
                const int d = dc * 8 + j;
                Vt[d * 36 + (((g ^ (d >> 3)) << 2) | wd)] =
                    ((unsigned int)v1[j] << 16) | (unsigned int)v0[j];
            }
        }
        __syncthreads();

#pragma unroll
        for (int sub = 0; sub < 2; ++sub) {
            // ---- QK^T ----
            f32x4 sc[4] = {};
#pragma unroll
            for (int i = 0; i < 4; ++i) {
                const int rb = i * 16 + cl;
#pragma unroll
                for (int ks = 0; ks < 2; ++ks) {
                    bf16x8 bk = *(const bf16x8*)(Ks + rb * 72 + quad * 8 + ks * 32);
                    sc[i] = __builtin_amdgcn_mfma_f32_16x16x32_bf16(aq[sub][ks], bk, sc[i],
                                                                    0, 0, 0);
                }
            }
            // ---- online softmax (rows quad*4+rr; max across 16 lanes of quad) ----
#pragma unroll
            for (int rr = 0; rr < 4; ++rr) {
                float rmax = fmaxf(fmaxf(sc[0][rr], sc[1][rr]), fmaxf(sc[2][rr], sc[3][rr]));
#pragma unroll
                for (int off = 1; off < 16; off <<= 1)
                    rmax = fmaxf(rmax, __shfl_xor(rmax, off, 16));
                const float mnew = fmaxf(m_r[sub][rr], rmax * 0.125f);
                const float alpha = __expf(m_r[sub][rr] - mnew);
                m_r[sub][rr] = mnew;
#pragma unroll
                for (int j = 0; j < 5; ++j) acc[sub][j][rr] *= alpha;
#pragma unroll
                for (int j = 0; j < 4; ++j) {
                    const float p = __expf(fmaf(sc[j][rr], 0.125f, -mnew));
                    Ps[(w * 32 + sub * 16 + quad * 4 + rr) * 72 + j * 16 + cl] = f2bf(p);
                }
            }
        }

        // ---- PV (+ l via ones-column) ----
#pragma unroll
        for (int ks = 0; ks < 2; ++ks) {
            bf16x8 bv[4];
#pragma unroll
            for (int j = 0; j < 4; ++j) {
                const int d = j * 16 + cl;
                bv[j] = *(const bf16x8*)(Vt + d * 36 + (((quad + 4 * ks) ^ (d >> 3)) << 2));
            }
#pragma unroll
            for (int sub = 0; sub < 2; ++sub) {
                bf16x8 ap =
                    *(const bf16x8*)(Ps + (w * 32 + sub * 16 + cl) * 72 + quad * 8 + ks * 32);
#pragma unroll
                for (int j = 0; j < 4; ++j)
                    acc[sub][j] =
                        __builtin_amdgcn_mfma_f32_16x16x32_bf16(ap, bv[j], acc[sub][j], 0, 0, 0);
                acc[sub][4] =
                    __builtin_amdgcn_mfma_f32_16x16x32_bf16(ap, vones, acc[sub][4], 0, 0, 0);
            }
        }
        __syncthreads();  // Ks/Vt/Ps reads done before next staging
    }

    // ---- epilogue: O = acc / l (l = ones-column), bf16 store ----
#pragma unroll
    for (int sub = 0; sub < 2; ++sub)
#pragma unroll
        for (int rr = 0; rr < 4; ++rr) {
            const float inv = 1.0f / acc[sub][4][rr];
            const size_t tok = tok0 + qt * 128 + w * 32 + sub * 16 + quad * 4 + rr;
#pragma unroll
            for (int j = 0; j < 4; ++j)
                ctx[tok * 1024 + h * 64 + j * 16 + cl] = f2bf(acc[sub][j][rr] * inv);
        }
}

extern "C" void kernel_launch(void* const* d_in, const int* in_sizes, int n_in,
                              void* d_out, int out_size, void* d_ws, size_t ws_size,
                              hipStream_t stream) {
    const float* x    = (const float*)d_in[0];
    const float* wqkv = (const float*)d_in[1];
    const float* bqkv = (const float*)d_in[2];
    const float* wo   = (const float*)d_in[3];
    const float* bo   = (const float*)d_in[4];
    const float* w1   = (const float*)d_in[5];
    const float* b1   = (const float*)d_in[6];
    const float* w2   = (const float*)d_in[7];
    const float* b2   = (const float*)d_in[8];
    const float* n1w  = (const float*)d_in[9];
    const float* n1b  = (const float*)d_in[10];
    const float* n2w  = (const float*)d_in[11];
    const float* n2b  = (const float*)d_in[12];
    float* out = (float*)d_out;   // also serves as x1 (residual stream after attention)

    char* ws = (char*)d_ws;
    unsigned short* wqkv_b = (unsigned short*)(ws);
    unsigned short* wo_b   = (unsigned short*)(ws + 6291456);
    unsigned short* w1_b   = (unsigned short*)(ws + 8388608);
    unsigned short* w2_b   = (unsigned short*)(ws + 16777216);
    unsigned short* r1     = (unsigned short*)(ws + 25165824);  // xn -> ctx -> xn2
    unsigned short* r2     = (unsigned short*)(ws + 58720256);  // qkv -> h chunks

    unsigned short* xn_b  = r1;
    unsigned short* ctx_b = r1;
    unsigned short* xn2_b = r1;
    unsigned short* qkv_b = r2;
    unsigned short* h_b   = r2;

    cvt_kernel<<<3072, 256, 0, stream>>>(wqkv, wqkv_b, 786432);
    cvt_kernel<<<1024, 256, 0, stream>>>(wo, wo_b, 262144);
    cvt_kernel<<<4096, 256, 0, stream>>>(w1, w1_b, 1048576);
    cvt_kernel<<<4096, 256, 0, stream>>>(w2, w2_b, 1048576);

    ln_kernel<<<16384, 256, 0, stream>>>(x, n1w, n1b, xn_b);
    gemm_bt<0><<<dim3(24, 128), 256, 0, stream>>>(xn_b, wqkv_b, bqkv, nullptr, qkv_b,
                                                  16384, 3072, 1024);
    attn_mfma<<<dim3(256, 8), 256, 0, stream>>>(qkv_b, ctx_b);
    gemm_bt<1><<<dim3(8, 128), 256, 0, stream>>>(ctx_b, wo_b, bo, x, out, 16384, 1024, 1024);
    ln_kernel<<<16384, 256, 0, stream>>>(out, n2w, n2b, xn2_b);

    for (int c = 0; c < 2; ++c) {
        const size_t row0 = (size_t)c * 8192;
        gemm_bt<2><<<dim3(32, 64), 256, 0, stream>>>(xn2_b + row0 * 1024, w1_b, b1, nullptr,
                                                     h_b, 8192, 4096, 1024);
        gemm_bt<1><<<dim3(8, 64), 256, 0, stream>>>(h_b, w2_b, b2, out + row0 * 1024,
                                                    out + row0 * 1024, 8192, 1024, 4096);
    }
}

// Round 6
// 912.991 us; speedup vs baseline: 1.1956x; 1.0973x over previous
//
#include <hip/hip_runtime.h>

// B=16,S=1024,E=1024,F=4096,H=16,D=64. N = B*S = 16384 tokens.
// Pipeline: LN1 -> QKV gemm(bf16 MFMA)+bias -> MFMA flash attn (S^T softmax) ->
//           proj gemm+bias+resid -> d_out -> LN2 -> lin1 gemm+bias+GELU ->
//           lin2 gemm+bias+resid(in-place d_out). FFN single-pass if ws allows, else 2-chunk.
//
// Workspace plan:
//   0          wqkv_b  bf16 3072x1024   (6 MB)
//   6291456    wo_b    bf16 1024x1024   (2 MB)
//   8388608    w1_b    bf16 4096x1024   (8 MB)
//   16777216   w2_b    bf16 1024x4096   (8 MB)
//   25165824   region1 (32 MB): xn_b -> ctx_b -> xn2_b
//   58720256   region2: qkv_b (96 MB) -> h (128 MB single-pass if ws_size>=184MiB,
//                                            else 64 MB chunks, 2-pass)
// x1 (fp32) lives in d_out; lin2 updates d_out in place (same-thread R->W).

typedef __attribute__((ext_vector_type(8))) short bf16x8;
typedef __attribute__((ext_vector_type(4))) float f32x4;
typedef __attribute__((ext_vector_type(8))) unsigned short u16x8;
typedef __attribute__((ext_vector_type(4))) unsigned short u16x4;

__device__ __forceinline__ float bf2f(unsigned short u) {
    return __uint_as_float(((unsigned int)u) << 16);
}
__device__ __forceinline__ unsigned short f2bf(float f) {
    unsigned int u = __float_as_uint(f);
    u += 0x7fffu + ((u >> 16) & 1u);   // RNE
    return (unsigned short)(u >> 16);
}
// pack two positive f32 into bf16x2 dword by truncation (P in [0,1])
__device__ __forceinline__ unsigned int pkbf_trunc(float a, float b) {
    return (__float_as_uint(a) >> 16) | (__float_as_uint(b) & 0xffff0000u);
}

// async global->LDS, 16 B per lane; LDS dest is wave-uniform base + lane*16
__device__ __forceinline__ void gload_lds16(const unsigned short* g, unsigned short* l) {
    __builtin_amdgcn_global_load_lds(
        (const __attribute__((address_space(1))) unsigned int*)g,
        (__attribute__((address_space(3))) unsigned int*)l, 16, 0, 0);
}

// ---------------- fp32 -> bf16 weight conversion ----------------
__global__ __launch_bounds__(256) void cvt_kernel(const float* __restrict__ in,
                                                  unsigned short* __restrict__ out, int n4) {
    int i = blockIdx.x * 256 + threadIdx.x;
    if (i >= n4) return;
    float4 v = ((const float4*)in)[i];
    u16x4 o;
    o[0] = f2bf(v.x); o[1] = f2bf(v.y); o[2] = f2bf(v.z); o[3] = f2bf(v.w);
    ((u16x4*)out)[i] = o;
}

// ---------------- LayerNorm (E=1024), fp32 in -> bf16 out ----------------
__global__ __launch_bounds__(256) void ln_kernel(const float* __restrict__ x,
                                                 const float* __restrict__ w,
                                                 const float* __restrict__ b,
                                                 unsigned short* __restrict__ out) {
    const int row = blockIdx.x;
    const int t = threadIdx.x;
    const float* xr = x + (size_t)row * 1024;
    float4 v = *(const float4*)(xr + t * 4);
    float s = v.x + v.y + v.z + v.w;
    float sq = v.x * v.x + v.y * v.y + v.z * v.z + v.w * v.w;
#pragma unroll
    for (int off = 32; off > 0; off >>= 1) {
        s += __shfl_xor(s, off);
        sq += __shfl_xor(sq, off);
    }
    __shared__ float rs_[4], rq_[4];
    if ((t & 63) == 0) { rs_[t >> 6] = s; rq_[t >> 6] = sq; }
    __syncthreads();
    s = rs_[0] + rs_[1] + rs_[2] + rs_[3];
    sq = rq_[0] + rq_[1] + rq_[2] + rq_[3];
    const float mu = s * (1.0f / 1024.0f);
    const float var = sq * (1.0f / 1024.0f) - mu * mu;
    const float rstd = rsqrtf(var + 1e-5f);
    const int c = t * 4;
    float4 wv = *(const float4*)(w + c);
    float4 bv = *(const float4*)(b + c);
    u16x4 o;
    o[0] = f2bf((v.x - mu) * rstd * wv.x + bv.x);
    o[1] = f2bf((v.y - mu) * rstd * wv.y + bv.y);
    o[2] = f2bf((v.z - mu) * rstd * wv.z + bv.z);
    o[3] = f2bf((v.w - mu) * rstd * wv.w + bv.w);
    *(u16x4*)(out + (size_t)row * 1024 + c) = o;
}

// ---------------- bf16 MFMA GEMM: C[M,N] = A[M,K] @ Bt[N,K]^T + epilogue ----------------
// 128x128 tile, BK=64 (32 KB LDS), 256 threads (4 waves, 2x2 of 64x64), 32 MFMAs per
// barrier pair. Async staging with global-side XOR swizzle (LDS slot s of row r holds
// global chunk s^(r&7)). EPI: 0 bias->bf16 ; 1 bias+resid->f32 ; 2 bias+GELU->bf16
template <int EPI>
__global__ __launch_bounds__(256) void gemm_bt(const unsigned short* __restrict__ A,
                                               const unsigned short* __restrict__ Bt,
                                               const float* __restrict__ bias,
                                               const float* __restrict__ resid,
                                               void* __restrict__ outp,
                                               int M, int N, int K) {
    __shared__ __align__(16) unsigned short sA[128 * 64];
    __shared__ __align__(16) unsigned short sB[128 * 64];
    const int t = threadIdx.x;
    const int lane = t & 63;
    const int w = t >> 6;
    const int wm = (w >> 1) * 64;
    const int wn = (w & 1) * 64;
    const int quad = lane >> 4;
    const int cl = lane & 15;
    const int mBase = blockIdx.y * 128;
    const int nBase = blockIdx.x * 128;

    const int rg = lane >> 3;                 // row within 8-row group
    const int gc = (lane & 7) ^ rg;           // fetched global 16B chunk (swizzled)
    const unsigned short* gA = A + (size_t)(mBase + w * 32 + rg) * K + gc * 8;
    const unsigned short* gB = Bt + (size_t)(nBase + w * 32 + rg) * K + gc * 8;

    f32x4 acc[4][4] = {};

    for (int k0 = 0; k0 < K; k0 += 64) {
#pragma unroll
        for (int u = 0; u < 4; ++u) {
            gload_lds16(gA + (size_t)u * 8 * K + k0, sA + (w * 4 + u) * 512);
            gload_lds16(gB + (size_t)u * 8 * K + k0, sB + (w * 4 + u) * 512);
        }
        __syncthreads();
#pragma unroll
        for (int ks = 0; ks < 2; ++ks) {
            bf16x8 af[4], bfr[4];
#pragma unroll
            for (int i = 0; i < 4; ++i) {
                const int ra = wm + i * 16 + cl;
                af[i] = *(const bf16x8*)(sA + ra * 64 + (((quad + 4 * ks) ^ (ra & 7)) * 8));
                const int rb = wn + i * 16 + cl;
                bfr[i] = *(const bf16x8*)(sB + rb * 64 + (((quad + 4 * ks) ^ (rb & 7)) * 8));
            }
#pragma unroll
            for (int i = 0; i < 4; ++i)
#pragma unroll
                for (int j = 0; j < 4; ++j)
                    acc[i][j] = __builtin_amdgcn_mfma_f32_16x16x32_bf16(af[i], bfr[j],
                                                                        acc[i][j], 0, 0, 0);
        }
        __syncthreads();
    }

    // C/D layout: col = lane&15, row = quad*4 + reg
#pragma unroll
    for (int i = 0; i < 4; ++i) {
        const int rowg = mBase + wm + i * 16 + quad * 4;
#pragma unroll
        for (int j = 0; j < 4; ++j) {
            const int colg = nBase + wn + j * 16 + cl;
            const float bv = bias[colg];
#pragma unroll
            for (int rr = 0; rr < 4; ++rr) {
                const float v = acc[i][j][rr] + bv;
                const size_t idx = (size_t)(rowg + rr) * N + colg;
                if constexpr (EPI == 0) {
                    ((unsigned short*)outp)[idx] = f2bf(v);
                } else if constexpr (EPI == 1) {
                    ((float*)outp)[idx] = v + resid[idx];
                } else {
                    const float g = 0.5f * v * (1.0f + erff(v * 0.70710678118654752f));
                    ((unsigned short*)outp)[idx] = f2bf(g);
                }
            }
        }
    }
}

// ---------------- MFMA flash attention, 128 q-rows/block, S^T softmax ----------------
// Block = 256 threads (4 waves). blockIdx.x = b*16+h, blockIdx.y = 128-row q-tile.
// Wave w owns q-rows qt*128 + w*32 .. +31 (two 16-row subs). Per 64-key tile:
//   S^T = mfma(K_frag, Q_frag): D[key=quad*4+rr (+i*16)][q=cl] — A/B frag layouts are
//   identical for 16x16x32, so operand swap is free. Each lane owns all 64 key-scores
//   of q=cl: max = 15 fmax + 2 shfl_xor(16,32); P packed to uint2 (trunc bf16, keys
//   consecutive) -> 4 ds_write_b64/sub; l rides a 5th PV accumulator vs ones B-frag
//   (same trunc P -> normalization-consistent); alpha rebroadcast to O rows via 4 shfl.
// LDS: Ks 9216 + Vt 9216 + Ps 18432 = 36.9 KB. 2 barriers/tile.
__global__ __launch_bounds__(256) void attn_mfma(const unsigned short* __restrict__ qkv,
                                                 unsigned short* __restrict__ ctx) {
    __shared__ __align__(16) unsigned short Ks[64 * 72];
    __shared__ __align__(16) unsigned int Vt[64 * 36];
    __shared__ __align__(16) unsigned short Ps[128 * 72];

    const int bh = blockIdx.x;
    const int qt = blockIdx.y;
    const int b = bh >> 4;
    const int h = bh & 15;
    const int t = threadIdx.x;
    const int w = t >> 6;
    const int lane = t & 63;
    const int quad = lane >> 4;
    const int cl = lane & 15;
    const size_t tok0 = (size_t)b * 1024;
    const int qrow0 = qt * 128 + w * 32;

    // Q fragments: operand [idx=cl][k=quad*8 + ks*32] (A/B identical layout)
    bf16x8 aq[2][2];
#pragma unroll
    for (int sub = 0; sub < 2; ++sub) {
        const unsigned short* qp =
            qkv + (tok0 + qrow0 + sub * 16 + cl) * 3072 + h * 64 + quad * 8;
        aq[sub][0] = *(const bf16x8*)(qp);
        aq[sub][1] = *(const bf16x8*)(qp + 32);
    }

    const bf16x8 vones = {0x3F80, 0x3F80, 0x3F80, 0x3F80, 0x3F80, 0x3F80, 0x3F80, 0x3F80};

    // staging indices
    const int r0 = t >> 2;         // K row 0..63
    const int c16 = (t & 3) * 16;  // K col chunk
    const int kp = t >> 3;         // V key-pair 0..31
    const int dc = t & 7;          // V d-chunk (8 d's)

    f32x4 acc[2][5] = {};          // [sub][j]; j=4 is the l-column (ones B-frag)
    float m_r[2] = {-3.0e38f, -3.0e38f};   // running max for q=cl, per sub

    for (int kt = 0; kt < 16; ++kt) {
        // ---- stage K [key][d] and V^T [d][key-pair dword] ----
        {
            const unsigned short* kg =
                qkv + (tok0 + kt * 64 + r0) * 3072 + 1024 + h * 64 + c16;
            *(int4*)(Ks + r0 * 72 + c16) = *(const int4*)(kg);
            *(int4*)(Ks + r0 * 72 + c16 + 8) = *(const int4*)(kg + 8);

            const unsigned short* vg =
                qkv + (tok0 + kt * 64 + 2 * kp) * 3072 + 2048 + h * 64 + dc * 8;
            u16x8 v0 = *(const u16x8*)(vg);
            u16x8 v1 = *(const u16x8*)(vg + 3072);
            const int g = kp >> 2, wd = kp & 3;
#pragma unroll
            for (int j = 0; j < 8; ++j) {
                const int d = dc * 8 + j;
                Vt[d * 36 + (((g ^ (d >> 3)) << 2) | wd)] =
                    ((unsigned int)v1[j] << 16) | (unsigned int)v0[j];
            }
        }
        __syncthreads();

#pragma unroll
        for (int sub = 0; sub < 2; ++sub) {
            // ---- S^T = K·Q^T (operand-swapped MFMA) ----
            f32x4 sc[4] = {};
#pragma unroll
            for (int i = 0; i < 4; ++i) {
                const int rb = i * 16 + cl;
#pragma unroll
                for (int ks = 0; ks < 2; ++ks) {
                    bf16x8 bk = *(const bf16x8*)(Ks + rb * 72 + quad * 8 + ks * 32);
                    sc[i] = __builtin_amdgcn_mfma_f32_16x16x32_bf16(bk, aq[sub][ks], sc[i],
                                                                    0, 0, 0);
                }
            }
            // ---- softmax for q = cl: all 64 key-scores live in this lane + 3 quad-mates
            float mx0 = fmaxf(fmaxf(sc[0][0], sc[0][1]), fmaxf(sc[0][2], sc[0][3]));
            float mx1 = fmaxf(fmaxf(sc[1][0], sc[1][1]), fmaxf(sc[1][2], sc[1][3]));
            float mx2 = fmaxf(fmaxf(sc[2][0], sc[2][1]), fmaxf(sc[2][2], sc[2][3]));
            float mx3 = fmaxf(fmaxf(sc[3][0], sc[3][1]), fmaxf(sc[3][2], sc[3][3]));
            float rmax = fmaxf(fmaxf(mx0, mx1), fmaxf(mx2, mx3));
            rmax = fmaxf(rmax, __shfl_xor(rmax, 16));
            rmax = fmaxf(rmax, __shfl_xor(rmax, 32));
            const float mnew = fmaxf(m_r[sub], rmax * 0.125f);
            const float alpha = __expf(m_r[sub] - mnew);
            m_r[sub] = mnew;
            // alpha for this lane's O rows (q = quad*4+rr) from lane cl'=quad*4+rr
            float al[4];
#pragma unroll
            for (int rr = 0; rr < 4; ++rr) al[rr] = __shfl(alpha, quad * 4 + rr, 16);
#pragma unroll
            for (int j = 0; j < 5; ++j)
#pragma unroll
                for (int rr = 0; rr < 4; ++rr) acc[sub][j][rr] *= al[rr];
            // P = exp(S - m) for 16 consecutive-key values; pack & store as 2 dwords/i
            const unsigned short* pr = Ps + (w * 32 + sub * 16 + cl) * 72;
#pragma unroll
            for (int i = 0; i < 4; ++i) {
                const float p0 = __expf(fmaf(sc[i][0], 0.125f, -mnew));
                const float p1 = __expf(fmaf(sc[i][1], 0.125f, -mnew));
                const float p2 = __expf(fmaf(sc[i][2], 0.125f, -mnew));
                const float p3 = __expf(fmaf(sc[i][3], 0.125f, -mnew));
                uint2 pk;
                pk.x = pkbf_trunc(p0, p1);
                pk.y = pkbf_trunc(p2, p3);
                *(uint2*)(pr + i * 16 + quad * 4) = pk;
            }
        }

        // ---- PV (+ l via ones-column) ----
#pragma unroll
        for (int ks = 0; ks < 2; ++ks) {
            bf16x8 bv[4];
#pragma unroll
            for (int j = 0; j < 4; ++j) {
                const int d = j * 16 + cl;
                bv[j] = *(const bf16x8*)(Vt + d * 36 + (((quad + 4 * ks) ^ (d >> 3)) << 2));
            }
#pragma unroll
            for (int sub = 0; sub < 2; ++sub) {
                bf16x8 ap =
                    *(const bf16x8*)(Ps + (w * 32 + sub * 16 + cl) * 72 + quad * 8 + ks * 32);
#pragma unroll
                for (int j = 0; j < 4; ++j)
                    acc[sub][j] =
                        __builtin_amdgcn_mfma_f32_16x16x32_bf16(ap, bv[j], acc[sub][j], 0, 0, 0);
                acc[sub][4] =
                    __builtin_amdgcn_mfma_f32_16x16x32_bf16(ap, vones, acc[sub][4], 0, 0, 0);
            }
        }
        __syncthreads();  // Ks/Vt reads done before next staging
    }

    // ---- epilogue: O = acc / l (l = ones-column), bf16 store ----
#pragma unroll
    for (int sub = 0; sub < 2; ++sub)
#pragma unroll
        for (int rr = 0; rr < 4; ++rr) {
            const float inv = 1.0f / acc[sub][4][rr];
            const size_t tok = tok0 + qt * 128 + w * 32 + sub * 16 + quad * 4 + rr;
#pragma unroll
            for (int j = 0; j < 4; ++j)
                ctx[tok * 1024 + h * 64 + j * 16 + cl] = f2bf(acc[sub][j][rr] * inv);
        }
}

extern "C" void kernel_launch(void* const* d_in, const int* in_sizes, int n_in,
                              void* d_out, int out_size, void* d_ws, size_t ws_size,
                              hipStream_t stream) {
    const float* x    = (const float*)d_in[0];
    const float* wqkv = (const float*)d_in[1];
    const float* bqkv = (const float*)d_in[2];
    const float* wo   = (const float*)d_in[3];
    const float* bo   = (const float*)d_in[4];
    const float* w1   = (const float*)d_in[5];
    const float* b1   = (const float*)d_in[6];
    const float* w2   = (const float*)d_in[7];
    const float* b2   = (const float*)d_in[8];
    const float* n1w  = (const float*)d_in[9];
    const float* n1b  = (const float*)d_in[10];
    const float* n2w  = (const float*)d_in[11];
    const float* n2b  = (const float*)d_in[12];
    float* out = (float*)d_out;   // also serves as x1 (residual stream after attention)

    char* ws = (char*)d_ws;
    unsigned short* wqkv_b = (unsigned short*)(ws);
    unsigned short* wo_b   = (unsigned short*)(ws + 6291456);
    unsigned short* w1_b   = (unsigned short*)(ws + 8388608);
    unsigned short* w2_b   = (unsigned short*)(ws + 16777216);
    unsigned short* r1     = (unsigned short*)(ws + 25165824);  // xn -> ctx -> xn2
    unsigned short* r2     = (unsigned short*)(ws + 58720256);  // qkv -> h

    unsigned short* xn_b  = r1;
    unsigned short* ctx_b = r1;
    unsigned short* xn2_b = r1;
    unsigned short* qkv_b = r2;
    unsigned short* h_b   = r2;

    cvt_kernel<<<3072, 256, 0, stream>>>(wqkv, wqkv_b, 786432);
    cvt_kernel<<<1024, 256, 0, stream>>>(wo, wo_b, 262144);
    cvt_kernel<<<4096, 256, 0, stream>>>(w1, w1_b, 1048576);
    cvt_kernel<<<4096, 256, 0, stream>>>(w2, w2_b, 1048576);

    ln_kernel<<<16384, 256, 0, stream>>>(x, n1w, n1b, xn_b);
    gemm_bt<0><<<dim3(24, 128), 256, 0, stream>>>(xn_b, wqkv_b, bqkv, nullptr, qkv_b,
                                                  16384, 3072, 1024);
    attn_mfma<<<dim3(256, 8), 256, 0, stream>>>(qkv_b, ctx_b);
    gemm_bt<1><<<dim3(8, 128), 256, 0, stream>>>(ctx_b, wo_b, bo, x, out, 16384, 1024, 1024);
    ln_kernel<<<16384, 256, 0, stream>>>(out, n2w, n2b, xn2_b);

    // FFN: single pass if h (128 MB @ region2) fits, else 2 row-chunks of 8192 tokens.
    // ws_size is constant across calls -> branch is graph-capture safe.
    if (ws_size >= 192937984ULL) {
        gemm_bt<2><<<dim3(32, 128), 256, 0, stream>>>(xn2_b, w1_b, b1, nullptr, h_b,
                                                      16384, 4096, 1024);
        gemm_bt<1><<<dim3(8, 128), 256, 0, stream>>>(h_b, w2_b, b2, out, out,
                                                     16384, 1024, 4096);
    } else {
        for (int c = 0; c < 2; ++c) {
            const size_t row0 = (size_t)c * 8192;
            gemm_bt<2><<<dim3(32, 64), 256, 0, stream>>>(xn2_b + row0 * 1024, w1_b, b1,
                                                         nullptr, h_b, 8192, 4096, 1024);
            gemm_bt<1><<<dim3(8, 64), 256, 0, stream>>>(h_b, w2_b, b2, out + row0 * 1024,
                                                        out + row0 * 1024, 8192, 1024, 4096);
        }
    }
}